// Round 2
// baseline (832.154 us; speedup 1.0000x reference)
//
#include <hip/hip_runtime.h>
#include <stdint.h>

// HashGrid3D, round 2: level-phased execution.
// Each XCD processes ONE level at a time so its 4 MB L2 holds exactly that
// level's 4 MB table. Output goes to a transposed workspace (coalesced
// nontemporal stores), then a transpose kernel produces the final layout.

constexpr int   LVL   = 16;
constexpr int   TBL   = 524288;          // 2^19 entries per level
constexpr uint32_t TMASK = 0x7FFFFu;     // T-1
constexpr uint32_t P2 = 2654435761u;
constexpr uint32_t P3 = 805459861u;
constexpr int RESV[LVL] = {16, 20, 25, 32, 40, 51, 64, 81,
                           102, 128, 161, 203, 256, 323, 406, 512};

typedef float v2f __attribute__((ext_vector_type(2)));
typedef float v4f __attribute__((ext_vector_type(4)));

// ---- core per-level evaluation (identical math to round 1, verified) ----
__device__ __forceinline__ v2f hg_eval(const float2* __restrict__ tbl, int N,
                                       float x, float y, float z)
{
    float Nf = (float)N;
    float sx = x * Nf, sy = y * Nf, sz = z * Nf;
    float fx = floorf(sx), fy = floorf(sy), fz = floorf(sz);
    float tx = sx - fx, ty = sy - fy, tz = sz - fz;
    int ix = (int)fx, iy = (int)fy, iz = (int)fz;

    int ix0 = (ix >= N) ? ix - N : ix;
    int iy0 = (iy >= N) ? iy - N : iy;
    int iz0 = (iz >= N) ? iz - N : iz;
    int ix1 = ix + 1; ix1 = (ix1 >= N) ? ix1 - N : ix1;
    int iy1 = iy + 1; iy1 = (iy1 >= N) ? iy1 - N : iy1;
    int iz1 = iz + 1; iz1 = (iz1 >= N) ? iz1 - N : iz1;

    uint32_t hx0 = (uint32_t)ix0;
    uint32_t hx1 = (uint32_t)ix1;
    uint32_t hy0 = (uint32_t)iy0 * P2;
    uint32_t hy1 = (uint32_t)iy1 * P2;
    uint32_t hz0 = (uint32_t)iz0 * P3;
    uint32_t hz1 = (uint32_t)iz1 * P3;

    float2 g000 = tbl[(hx0 ^ hy0 ^ hz0) & TMASK];
    float2 g100 = tbl[(hx1 ^ hy0 ^ hz0) & TMASK];
    float2 g010 = tbl[(hx0 ^ hy1 ^ hz0) & TMASK];
    float2 g110 = tbl[(hx1 ^ hy1 ^ hz0) & TMASK];
    float2 g001 = tbl[(hx0 ^ hy0 ^ hz1) & TMASK];
    float2 g101 = tbl[(hx1 ^ hy0 ^ hz1) & TMASK];
    float2 g011 = tbl[(hx0 ^ hy1 ^ hz1) & TMASK];
    float2 g111 = tbl[(hx1 ^ hy1 ^ hz1) & TMASK];

    float wx1 = tx, wx0 = 1.0f - tx;
    float wy1 = ty, wy0 = 1.0f - ty;
    float wz1 = tz, wz0 = 1.0f - tz;
    float wz0y0 = wy0 * wz0, wz0y1 = wy1 * wz0;
    float wz1y0 = wy0 * wz1, wz1y1 = wy1 * wz1;
    float w000 = wx0 * wz0y0, w100 = wx1 * wz0y0;
    float w010 = wx0 * wz0y1, w110 = wx1 * wz0y1;
    float w001 = wx0 * wz1y0, w101 = wx1 * wz1y0;
    float w011 = wx0 * wz1y1, w111 = wx1 * wz1y1;

    v2f r;
    r.x = w000 * g000.x + w100 * g100.x + w010 * g010.x + w110 * g110.x
        + w001 * g001.x + w101 * g101.x + w011 * g011.x + w111 * g111.x;
    r.y = w000 * g000.y + w100 * g100.y + w010 * g010.y + w110 * g110.y
        + w001 * g001.y + w101 * g101.y + w011 * g011.y + w111 * g111.y;
    return r;
}

// ---- level-phased kernel: one (level, 256-point chunk) per block ----
// Block mapping: slot = b % (8*BPL); xcd = slot % 8; phase = b / (8*BPL).
// level = phase==0 ? xcd : 15-xcd  (balances coarse+fine per XCD).
__global__ __launch_bounds__(256)
void hg_level_kernel(const float* __restrict__ xyt,
                     const float* __restrict__ tables,
                     float* __restrict__ out_t, int n, int BPL)
{
    int b = blockIdx.x;
    int half = 8 * BPL;
    int phase = b / half;
    int slot  = b - phase * half;
    int xcd   = slot & 7;
    int chunk = slot >> 3;
    int level = (phase == 0) ? xcd : (15 - xcd);

    int p = chunk * 256 + threadIdx.x;
    if (p >= n) return;

    float x = xyt[3 * p + 0];
    float y = xyt[3 * p + 1];
    float z = xyt[3 * p + 2];

    const float2* __restrict__ tbl = (const float2*)tables + (size_t)level * TBL;
    v2f r = hg_eval(tbl, RESV[level], x, y, z);

    // coalesced 8 B/lane store, nontemporal so it doesn't evict the table
    v2f* dst = (v2f*)out_t + (size_t)level * n + p;
    __builtin_nontemporal_store(r, dst);
}

// ---- transpose: out_t[16][n][2] -> out[n][32]; coalesced both sides ----
__global__ __launch_bounds__(256)
void hg_transpose_kernel(const float* __restrict__ out_t,
                         float* __restrict__ out, int n)
{
    int p = blockIdx.x * 256 + threadIdx.x;
    if (p >= n) return;

    v4f buf[8];
    v2f* b2 = (v2f*)buf;
    #pragma unroll
    for (int l = 0; l < LVL; ++l) {
        const v2f* src = (const v2f*)out_t + (size_t)l * n + p;
        b2[l] = __builtin_nontemporal_load(src);
    }
    v4f* o = (v4f*)(out + (size_t)p * 32);
    #pragma unroll
    for (int i = 0; i < 8; ++i)
        __builtin_nontemporal_store(buf[i], o + i);
}

// ---- fallback: round-1 monolithic kernel (used if ws too small) ----
__global__ __launch_bounds__(256)
void hg_mono_kernel(const float* __restrict__ xyt,
                    const float* __restrict__ tables,
                    float* __restrict__ out, int n)
{
    int p = blockIdx.x * 256 + threadIdx.x;
    if (p >= n) return;

    float x = xyt[3 * p + 0];
    float y = xyt[3 * p + 1];
    float z = xyt[3 * p + 2];

    float outv[2 * LVL];
    #pragma unroll
    for (int l = 0; l < LVL; ++l) {
        const float2* __restrict__ tbl = (const float2*)tables + (size_t)l * TBL;
        v2f r = hg_eval(tbl, RESV[l], x, y, z);
        outv[2 * l + 0] = r.x;
        outv[2 * l + 1] = r.y;
    }
    float4* o = (float4*)(out + (size_t)p * 32);
    #pragma unroll
    for (int i = 0; i < 8; ++i)
        o[i] = ((const float4*)outv)[i];
}

extern "C" void kernel_launch(void* const* d_in, const int* in_sizes, int n_in,
                              void* d_out, int out_size, void* d_ws, size_t ws_size,
                              hipStream_t stream) {
    const float* xyt    = (const float*)d_in[0];   // (n, 3) f32
    const float* tables = (const float*)d_in[1];   // (16, 524288, 2) f32
    float* out = (float*)d_out;                    // (n, 32) f32
    int n = in_sizes[0] / 3;

    size_t ws_needed = (size_t)LVL * (size_t)n * 2 * sizeof(float);
    if (ws_size >= ws_needed) {
        float* out_t = (float*)d_ws;
        int BPL = (n + 255) / 256;             // blocks per level
        int grid = 16 * BPL;                   // 2 phases * 8 xcd * BPL
        hg_level_kernel<<<grid, 256, 0, stream>>>(xyt, tables, out_t, n, BPL);
        hg_transpose_kernel<<<BPL, 256, 0, stream>>>(out_t, out, n);
    } else {
        int blocks = (n + 255) / 256;
        hg_mono_kernel<<<blocks, 256, 0, stream>>>(xyt, tables, out, n);
    }
}